// Round 3
// baseline (1125.642 us; speedup 1.0000x reference)
//
#include <hip/hip_runtime.h>
#include <hip/hip_cooperative_groups.h>
#include <math.h>

#define DIM 4096
#define RDIM 16
#define RIDGE 1e-5f
#define NPKP 144    // padded pair count (9 MFMA tiles of 16)
#define KCH 16      // K-chunks for MFMA buildA
#define KT 64       // k-tile staged in LDS per buildA inner iteration
#define NSL 64      // tpart slices (= row-slice count for it_c)
#define SROWS 64    // rows per iteration-phase slice
#define NBLK 1024   // grid: 1024 blocks = 4/CU on 256 CUs
#define SMEM_BYTES ((64 + 144) * (KT + 8) * 2)   // 29,952 B union buffer

namespace cg = cooperative_groups;

typedef __attribute__((ext_vector_type(8))) short bf16x8;
typedef __attribute__((ext_vector_type(4))) float f32x4;

__device__ __forceinline__ int pidx(int r, int s) { return r * (31 - r) / 2 + s; } // r<=s

__device__ __forceinline__ float alpha_of(float cl) {
    return cl * (1.f - erff(sqrtf(cl))) +
           0.5f * (erff(cl * 0.70710678118f) -
                   0.79788456080f * cl * expf(-0.5f * cl * cl));
}

__device__ __forceinline__ unsigned short bf16_rne(float p) {
    unsigned bits = __float_as_uint(p);
    return (unsigned short)((bits + 0x7FFFu + ((bits >> 16) & 1u)) >> 16);
}

// ------- transpose X -> Xt, fused per-column and per-row observed counts ---
__global__ void __launch_bounds__(256) k_transpose(const float* __restrict__ X,
                                                   float* __restrict__ Xt,
                                                   float* __restrict__ cntc,
                                                   float* __restrict__ cntr) {
    __shared__ float tile[64][65];
    __shared__ float redc[4][64];
    __shared__ float redr[4][64];
    int bx = blockIdx.x, by = blockIdx.y;
    int lx = threadIdx.x & 63;
    int ly = threadIdx.x >> 6;
    float ccnt = 0.f;
#pragma unroll
    for (int i = 0; i < 16; ++i) {
        int r = ly + i * 4;
        float v = X[(size_t)(by * 64 + r) * DIM + bx * 64 + lx];
        tile[r][lx] = v;
        ccnt += (v != 0.f) ? 1.f : 0.f;
    }
    redc[ly][lx] = ccnt;
    __syncthreads();
#pragma unroll
    for (int i = 0; i < 16; ++i) {
        int r = ly + i * 4;
        Xt[(size_t)(bx * 64 + r) * DIM + by * 64 + lx] = tile[lx][r];
    }
    float rcnt = 0.f;
#pragma unroll
    for (int j = 0; j < 16; ++j)
        rcnt += (tile[lx][ly * 16 + j] != 0.f) ? 1.f : 0.f;
    redr[ly][lx] = rcnt;
    __syncthreads();
    if (threadIdx.x < 64) {
        int c = threadIdx.x;
        atomicAdd(&cntc[bx * 64 + c],
                  redc[0][c] + redc[1][c] + redc[2][c] + redc[3][c]);
    } else if (threadIdx.x < 128) {
        int r = threadIdx.x - 64;
        atomicAdd(&cntr[by * 64 + r],
                  redr[0][r] + redr[1][r] + redr[2][r] + redr[3][r]);
    }
}

// ---------------- init copies ----------------------------------------------
__global__ void k_init_uc(const float* __restrict__ U, float* __restrict__ Uc) {
    int i = blockIdx.x * 256 + threadIdx.x;
    ((float4*)Uc)[i] = ((const float4*)U)[i];
}
__global__ void k_init_vt(const float* __restrict__ V, float* __restrict__ Vtb) {
    int n = blockIdx.x * 256 + threadIdx.x;
#pragma unroll
    for (int r = 0; r < RDIM; ++r) Vtb[(size_t)n * RDIM + r] = V[(size_t)r * DIM + n];
}

// ---------------- Pt[rs][m] = bf16(D[m][r] * D[m][s]), pidx order ----------
// Only used ONCE (layer-0 V step); later Pt builds fused into phase D2.
__global__ void __launch_bounds__(256) k_prep(const float* __restrict__ D,
                                              unsigned short* __restrict__ Pt) {
    int rs = blockIdx.y;
    int rr = 16, ss = 0;
#pragma unroll
    for (int r = 0; r < 16; ++r) {
        int base = r * (31 - r) / 2;
        if (rs >= base + r && rs <= base + 15) { rr = r; ss = rs - base; }
    }
    int m = blockIdx.x * 256 + threadIdx.x;
    float p = 0.f;
    if (rr < 16) p = D[(size_t)m * RDIM + rr] * D[(size_t)m * RDIM + ss];
    Pt[(size_t)rs * DIM + m] = bf16_rne(p);
}

// ======================= half-step phase bodies ============================
// All phases use linear bid in [0, NBLK); block = 256 threads (except where
// fewer are active via guards). smem = per-kernel LDS union buffer.

// ---- phase B: MFMA buildA. (bid&63) = c-block, (bid>>6) = k-chunk (0..15) -
__device__ __forceinline__ void d_buildA(unsigned char* smem,
                                         const float* __restrict__ XpT,
                                         const unsigned short* __restrict__ Pt,
                                         float* __restrict__ Apad) {
    unsigned short (*wtile)[KT + 8] = (unsigned short (*)[KT + 8])smem;             // 64 x 72
    unsigned short (*ptile)[KT + 8] =
        (unsigned short (*)[KT + 8])(smem + 64 * (KT + 8) * 2);                     // 144 x 72
    const int tid = threadIdx.x;
    const int wave = tid >> 6;
    const int lane = tid & 63;
    const int n = lane & 15;
    const int quad = lane >> 4;
    const int c0 = (blockIdx.x & 63) * 64;
    const int kch = blockIdx.x >> 6;            // 0..15
    const int kbase0 = kch * (DIM / KCH);       // *256
    const int r0 = tid >> 4;                    // 0..15
    const int col4 = (tid & 15) * 4;            // 0..60

    f32x4 acc[9];
#pragma unroll
    for (int t = 0; t < 9; ++t) acc[t] = (f32x4){0.f, 0.f, 0.f, 0.f};

    for (int kt = 0; kt < (DIM / KCH) / KT; ++kt) {   // 4 iterations
        const int kb = kbase0 + kt * KT;
        __syncthreads();
        // stage W mask: 64 rows x 64 cols, coalesced float4 reads
#pragma unroll
        for (int j = 0; j < 4; ++j) {
            int r = r0 + 16 * j;
            float4 v = *(const float4*)(XpT + (size_t)(c0 + r) * DIM + kb + col4);
            ushort4 mk;
            mk.x = (v.x != 0.f) ? 0x3F80 : 0;
            mk.y = (v.y != 0.f) ? 0x3F80 : 0;
            mk.z = (v.z != 0.f) ? 0x3F80 : 0;
            mk.w = (v.w != 0.f) ? 0x3F80 : 0;
            *(ushort4*)&wtile[r][col4] = mk;
        }
        // stage Pt: 144 rows x 64 bf16 = 2304 8B-chunks = 256 thr x 9
#pragma unroll
        for (int j = 0; j < 9; ++j) {
            int idx = j * 256 + tid;
            int pr = idx >> 4;
            int pc = (idx & 15) * 4;
            *(ushort4*)&ptile[pr][pc] = *(const ushort4*)(Pt + (size_t)pr * DIM + kb + pc);
        }
        __syncthreads();
#pragma unroll
        for (int inner = 0; inner < 2; ++inner) {
            bf16x8 bfrag = *(const bf16x8*)&wtile[wave * 16 + n][inner * 32 + quad * 8];
#pragma unroll
            for (int t = 0; t < 9; ++t) {
                bf16x8 afrag = *(const bf16x8*)&ptile[t * 16 + n][inner * 32 + quad * 8];
                acc[t] = __builtin_amdgcn_mfma_f32_16x16x32_bf16(afrag, bfrag, acc[t], 0, 0, 0);
            }
        }
    }
    const int c = c0 + wave * 16 + n;
    float* dst0 = Apad + ((size_t)kch * DIM + c) * NPKP + quad * 4;
#pragma unroll
    for (int t = 0; t < 9; ++t)
        *(float4*)(dst0 + t * 16) = (float4){acc[t].x, acc[t].y, acc[t].z, acc[t].w};
}

// ---- phase I: invert 16x16 SPD; chunk reduction fused; zeros snum[0..1] ---
// 4 matrices per block (tid<64 active); c = bid*4 + (tid>>4).
__device__ __forceinline__ void d_invert(const float* __restrict__ Apad,
                                         float* __restrict__ Ainv,
                                         float* __restrict__ snum) {
    const int tid = threadIdx.x;
    if (tid >= 64) return;
    int c = blockIdx.x * 4 + (tid >> 4);
    int j = tid & 15;
    if (j == 0) { snum[c] = 0.f; snum[c + DIM] = 0.f; }

    float a[16], b[16];
#pragma unroll
    for (int s = 0; s < 16; ++s) {
        int r0 = j < s ? j : s;
        int s0 = j < s ? s : j;
        int off = pidx(r0, s0);
        float acc = 0.f;
#pragma unroll
        for (int ch = 0; ch < KCH; ++ch)
            acc += Apad[((size_t)ch * DIM + c) * NPKP + off];
        a[s] = acc;
        b[s] = 0.f;
    }
    a[j] += RIDGE;
    b[j] = 1.f;

#pragma unroll
    for (int k = 0; k < RDIM; ++k) {
        float pivA[16], pivB[16];
#pragma unroll
        for (int s = 0; s < 16; ++s) {
            pivA[s] = __shfl(a[s], k, 16);
            pivB[s] = __shfl(b[s], k, 16);
        }
        float pinv = 1.f / pivA[k];
        float f = a[k];
        if (j == k) {
#pragma unroll
            for (int s = 0; s < 16; ++s) { a[s] = pivA[s] * pinv; b[s] = pivB[s] * pinv; }
        } else {
#pragma unroll
            for (int s = 0; s < 16; ++s) {
                a[s] -= f * pinv * pivA[s];
                b[s] -= f * pinv * pivB[s];
            }
        }
    }
#pragma unroll
    for (int s = 0; s < 16; ++s) Ainv[(size_t)c * 256 + j * 16 + s] = b[s];
}

// ---- phase A: psi^2 partials -> atomic snum_wr ----------------------------
// (bid&15) = col group (256 cols, 1/thread), (bid>>4) = 64-row slice (0..63).
__device__ __forceinline__ void d_it_a(unsigned char* smem,
                                       const float* __restrict__ Xp,
                                       const float* __restrict__ D,
                                       const float* __restrict__ B,
                                       const float* __restrict__ snum_rd,
                                       const float* __restrict__ sigma,
                                       const float* __restrict__ cnt,
                                       const float* __restrict__ cvec,
                                       const float* __restrict__ lvec,
                                       int layer, int use_s0,
                                       float* __restrict__ snum_wr) {
    float* ds = (float*)smem;                  // SROWS*RDIM floats = 4 KB
    const int tid = threadIdx.x;
    const int c = (blockIdx.x & 15) * 256 + tid;
    const int m0 = (blockIdx.x >> 4) * SROWS;
    ((float4*)ds)[tid] = ((const float4*)(D + (size_t)m0 * RDIM))[tid];

    float cl = cvec[layer];
    float invsg;
    if (use_s0) {
        invsg = 1.f / sigma[0];
    } else {
        float ll = lvec[layer];
        float al = alpha_of(cl);
        invsg = 1.f / (ll * sqrtf(snum_rd[c]) * rsqrtf(2.f * cnt[c] * al));
    }
    float beta[16];
#pragma unroll
    for (int q = 0; q < 4; ++q) {
        float4 t4 = ((const float4*)(B + (size_t)c * RDIM))[q];
        beta[q * 4 + 0] = t4.x; beta[q * 4 + 1] = t4.y;
        beta[q * 4 + 2] = t4.z; beta[q * 4 + 3] = t4.w;
    }
    __syncthreads();

    float acc = 0.f;
#pragma unroll 4
    for (int m = 0; m < SROWS; ++m) {
        float u[16];
#pragma unroll
        for (int q = 0; q < 4; ++q) {
            float4 u4 = ((const float4*)(ds + m * RDIM))[q];
            u[q * 4 + 0] = u4.x; u[q * 4 + 1] = u4.y;
            u[q * 4 + 2] = u4.z; u[q * 4 + 3] = u4.w;
        }
        float xv = Xp[(size_t)(m0 + m) * DIM + c];
        float dot = 0.f;
#pragma unroll
        for (int s = 0; s < 16; ++s) dot += u[s] * beta[s];
        float res = (xv != 0.f) ? (xv - dot) : 0.f;
        float psi = fminf(fmaxf(res * invsg, -cl), cl);
        acc += psi * psi;
    }
    atomicAdd(&snum_wr[c], acc);
}

// ---- phase C: t slice partials, sig computed inline -----------------------
__device__ __forceinline__ void d_it_c(unsigned char* smem,
                                       const float* __restrict__ Xp,
                                       const float* __restrict__ D,
                                       const float* __restrict__ B,
                                       const float* __restrict__ snum_rd,
                                       const float* __restrict__ cnt,
                                       const float* __restrict__ cvec,
                                       const float* __restrict__ lvec,
                                       int layer,
                                       float* __restrict__ tpart) {
    float* ds = (float*)smem;                  // 4 KB
    const int tid = threadIdx.x;
    const int c = (blockIdx.x & 15) * 256 + tid;
    const int m0 = (blockIdx.x >> 4) * SROWS;
    ((float4*)ds)[tid] = ((const float4*)(D + (size_t)m0 * RDIM))[tid];

    float cl = cvec[layer];
    float ll = lvec[layer];
    float al = alpha_of(cl);
    float sg = ll * sqrtf(snum_rd[c]) * rsqrtf(2.f * cnt[c] * al);
    float invsg = 1.f / sg;
    float beta[16];
#pragma unroll
    for (int q = 0; q < 4; ++q) {
        float4 t4 = ((const float4*)(B + (size_t)c * RDIM))[q];
        beta[q * 4 + 0] = t4.x; beta[q * 4 + 1] = t4.y;
        beta[q * 4 + 2] = t4.z; beta[q * 4 + 3] = t4.w;
    }
    __syncthreads();

    float tac[16];
#pragma unroll
    for (int s = 0; s < 16; ++s) tac[s] = 0.f;

#pragma unroll 2
    for (int m = 0; m < SROWS; ++m) {
        float u[16];
#pragma unroll
        for (int q = 0; q < 4; ++q) {
            float4 u4 = ((const float4*)(ds + m * RDIM))[q];
            u[q * 4 + 0] = u4.x; u[q * 4 + 1] = u4.y;
            u[q * 4 + 2] = u4.z; u[q * 4 + 3] = u4.w;
        }
        float xv = Xp[(size_t)(m0 + m) * DIM + c];
        float dot = 0.f;
#pragma unroll
        for (int s = 0; s < 16; ++s) dot += u[s] * beta[s];
        float res = (xv != 0.f) ? (xv - dot) : 0.f;
        float psi2 = fminf(fmaxf(res * invsg, -cl), cl);
        float coeff = psi2 * sg;
#pragma unroll
        for (int s = 0; s < 16; ++s) tac[s] += u[s] * coeff;
    }
    float* tsl = tpart + (size_t)(blockIdx.x >> 4) * DIM * RDIM;
#pragma unroll
    for (int q = 0; q < 4; ++q)
        *(float4*)(tsl + (size_t)c * RDIM + q * 4) =
            make_float4(tac[q * 4 + 0], tac[q * 4 + 1], tac[q * 4 + 2], tac[q * 4 + 3]);
}

// ---- phase D: B += mu * Ainv @ (sum of tpart slices); optional Pt build ---
// 4 cols per block (tid<64 active for main work).
__device__ __forceinline__ void d_it_d(unsigned char* smem,
                                       const float* __restrict__ Ainv,
                                       const float* __restrict__ tpart,
                                       const float* __restrict__ mvec, int layer,
                                       float* __restrict__ B,
                                       unsigned short* __restrict__ Pt, int do_pt) {
    float (*t_sh)[16] = (float (*)[16])smem;            // 4 x 16
    unsigned char* prr = smem + 256;
    unsigned char* pss = smem + 256 + 144;
    const int tid = threadIdx.x;
    if (do_pt && tid < 144) {
        int rs = tid;
        int rr = 255, ss = 0;
#pragma unroll
        for (int r = 0; r < 16; ++r) {
            int base = r * (31 - r) / 2;
            if (rs >= base + r && rs <= base + 15) { rr = r; ss = rs - base; }
        }
        prr[rs] = (unsigned char)rr;
        pss[rs] = (unsigned char)ss;
    }
    const int c0 = blockIdx.x * 4;
    const int cl_ = tid >> 4;
    const int j = tid & 15;
    if (tid < 64) {
        float tv = 0.f;
#pragma unroll 8
        for (int sl = 0; sl < NSL; ++sl)
            tv += tpart[((size_t)sl * DIM + c0 + cl_) * RDIM + j];
        t_sh[cl_][j] = tv;
    }
    __syncthreads();
    if (tid < 64) {
        int c = c0 + cl_;
        float ml = mvec[layer];
        float d = 0.f;
#pragma unroll
        for (int q = 0; q < 4; ++q) {
            float4 a4 = *(const float4*)(Ainv + (size_t)c * 256 + j * 16 + q * 4);
            d += a4.x * t_sh[cl_][q * 4 + 0] + a4.y * t_sh[cl_][q * 4 + 1] +
                 a4.z * t_sh[cl_][q * 4 + 2] + a4.w * t_sh[cl_][q * 4 + 3];
        }
        float bnew = B[(size_t)c * RDIM + j] + ml * d;
        B[(size_t)c * RDIM + j] = bnew;

        if (do_pt) {
            int gbase = tid & 48;   // 16-lane group base within wave
#pragma unroll
            for (int t = 0; t < 9; ++t) {
                int rs = t * 16 + j;
                int rr = prr[rs], ss2 = pss[rs];
                float brr = __shfl(bnew, gbase + (rr & 15), 64);
                float bss = __shfl(bnew, gbase + (ss2 & 15), 64);
                float p = (rr < 16) ? brr * bss : 0.f;
                Pt[(size_t)rs * DIM + c] = bf16_rne(p);
            }
        }
    }
}

// =================== fused half-step (cooperative kernel) ==================
struct HSArgs {
    const float* XpT;            // design-orientation matrix for buildA mask
    const float* Xp;             // iteration-orientation matrix
    const unsigned short* PtIn;  // pair-products for buildA
    unsigned short* PtOut;       // pair-products for NEXT half-step (or null)
    float* Apad;                 // aliases tpart
    float* Ainv;
    float* tpart;
    float* snum;                 // [2*DIM] ping-pong psi^2 sums
    const float* sigma;
    const float* cnt;
    const float* cvec;
    const float* lvec;
    const float* mvec;
    const float* D;              // design matrix (read-only this half-step)
    float* B;                    // beta being updated
    int layer;
    int do_pt;
};

__global__ void __launch_bounds__(256, 4) k_halfstep(HSArgs a) {
    __shared__ __align__(16) unsigned char smem[SMEM_BYTES];   // union for all phases
    cg::grid_group grid = cg::this_grid();
    d_buildA(smem, a.XpT, a.PtIn, a.Apad);
    grid.sync();
    d_invert(a.Apad, a.Ainv, a.snum);          // also zeros snum[0..1]
    grid.sync();
    // ---- hubreg iteration 1 ----
    d_it_a(smem, a.Xp, a.D, a.B, a.snum, a.sigma, a.cnt, a.cvec, a.lvec, a.layer, 1, a.snum);
    grid.sync();
    d_it_c(smem, a.Xp, a.D, a.B, a.snum, a.cnt, a.cvec, a.lvec, a.layer, a.tpart);
    grid.sync();
    d_it_d(smem, a.Ainv, a.tpart, a.mvec, a.layer, a.B, nullptr, 0);
    grid.sync();
    // ---- hubreg iteration 2 ----
    d_it_a(smem, a.Xp, a.D, a.B, a.snum, a.sigma, a.cnt, a.cvec, a.lvec, a.layer, 0, a.snum + DIM);
    grid.sync();
    d_it_c(smem, a.Xp, a.D, a.B, a.snum + DIM, a.cnt, a.cvec, a.lvec, a.layer, a.tpart);
    grid.sync();
    d_it_d(smem, a.Ainv, a.tpart, a.mvec, a.layer, a.B, a.PtOut, a.do_pt);
}

// ============ fallback: same phase bodies as separate launches =============
__global__ void __launch_bounds__(256) g_buildA(const float* XpT,
                                                const unsigned short* Pt, float* Apad) {
    __shared__ __align__(16) unsigned char smem[SMEM_BYTES];
    d_buildA(smem, XpT, Pt, Apad);
}
__global__ void __launch_bounds__(64) g_invert(const float* Apad, float* Ainv, float* snum) {
    d_invert(Apad, Ainv, snum);
}
__global__ void __launch_bounds__(256) g_it_a(const float* Xp, const float* D, const float* B,
                                              const float* snum_rd, const float* sigma,
                                              const float* cnt, const float* cvec,
                                              const float* lvec, int layer, int use_s0,
                                              float* snum_wr) {
    __shared__ __align__(16) unsigned char smem[4096];
    d_it_a(smem, Xp, D, B, snum_rd, sigma, cnt, cvec, lvec, layer, use_s0, snum_wr);
}
__global__ void __launch_bounds__(256) g_it_c(const float* Xp, const float* D, const float* B,
                                              const float* snum_rd, const float* cnt,
                                              const float* cvec, const float* lvec,
                                              int layer, float* tpart) {
    __shared__ __align__(16) unsigned char smem[4096];
    d_it_c(smem, Xp, D, B, snum_rd, cnt, cvec, lvec, layer, tpart);
}
__global__ void __launch_bounds__(256) g_it_d(const float* Ainv, const float* tpart,
                                              const float* mvec, int layer, float* B,
                                              unsigned short* Pt, int do_pt) {
    __shared__ __align__(16) unsigned char smem[1024];
    d_it_d(smem, Ainv, tpart, mvec, layer, B, Pt, do_pt);
}

// ---------------- final out = Uc @ Vtb^T -----------------------------------
__global__ void __launch_bounds__(256) k_out(const float* __restrict__ Uc,
                                             const float* __restrict__ Vtb,
                                             float* __restrict__ out) {
    __shared__ float us[64 * RDIM];
    int j = blockIdx.x * 256 + threadIdx.x;
    int i0 = blockIdx.y * 64;
    ((float4*)us)[threadIdx.x] = ((const float4*)(Uc + (size_t)i0 * RDIM))[threadIdx.x];
    float beta[16];
#pragma unroll
    for (int q = 0; q < 4; ++q) {
        float4 t4 = ((const float4*)(Vtb + (size_t)j * RDIM))[q];
        beta[q * 4 + 0] = t4.x; beta[q * 4 + 1] = t4.y;
        beta[q * 4 + 2] = t4.z; beta[q * 4 + 3] = t4.w;
    }
    __syncthreads();
#pragma unroll 4
    for (int r = 0; r < 64; ++r) {
        float dot = 0.f;
#pragma unroll
        for (int q = 0; q < 4; ++q) {
            float4 u4 = *(const float4*)(us + r * RDIM + q * 4);
            dot += u4.x * beta[q * 4 + 0] + u4.y * beta[q * 4 + 1] +
                   u4.z * beta[q * 4 + 2] + u4.w * beta[q * 4 + 3];
        }
        out[(size_t)(i0 + r) * DIM + j] = dot;
    }
}

static void run_halfstep(const HSArgs& a, hipStream_t stream, int coop) {
    if (coop) {
        HSArgs tmp = a;
        void* params[1] = { (void*)&tmp };
        (void)hipLaunchCooperativeKernel(k_halfstep, dim3(NBLK), dim3(256),
                                         params, 0u, stream);
        return;
    }
    g_buildA<<<NBLK, 256, 0, stream>>>(a.XpT, a.PtIn, a.Apad);
    g_invert<<<NBLK, 64, 0, stream>>>(a.Apad, a.Ainv, a.snum);
    g_it_a<<<NBLK, 256, 0, stream>>>(a.Xp, a.D, a.B, a.snum, a.sigma, a.cnt,
                                     a.cvec, a.lvec, a.layer, 1, a.snum);
    g_it_c<<<NBLK, 256, 0, stream>>>(a.Xp, a.D, a.B, a.snum, a.cnt,
                                     a.cvec, a.lvec, a.layer, a.tpart);
    g_it_d<<<NBLK, 256, 0, stream>>>(a.Ainv, a.tpart, a.mvec, a.layer, a.B, nullptr, 0);
    g_it_a<<<NBLK, 256, 0, stream>>>(a.Xp, a.D, a.B, a.snum, a.sigma, a.cnt,
                                     a.cvec, a.lvec, a.layer, 0, a.snum + DIM);
    g_it_c<<<NBLK, 256, 0, stream>>>(a.Xp, a.D, a.B, a.snum + DIM, a.cnt,
                                     a.cvec, a.lvec, a.layer, a.tpart);
    g_it_d<<<NBLK, 256, 0, stream>>>(a.Ainv, a.tpart, a.mvec, a.layer, a.B,
                                     a.PtOut, a.do_pt);
}

extern "C" void kernel_launch(void* const* d_in, const int* in_sizes, int n_in,
                              void* d_out, int out_size, void* d_ws, size_t ws_size,
                              hipStream_t stream) {
    const float* U = (const float*)d_in[0];
    const float* V = (const float*)d_in[1];
    const float* X = (const float*)d_in[2];
    const float* cvec = (const float*)d_in[3];
    const float* lvec = (const float*)d_in[4];
    const float* mvec = (const float*)d_in[5];
    const float* sigma = (const float*)d_in[6];
    float* out = (float*)d_out;

    // Decide cooperative vs split ONCE, via pure queries (no trial launches).
    static int coop_mode = -1;
    if (coop_mode < 0) {
        int dev = 0, coop_attr = 0, ncu = 0, occ = 0;
        (void)hipGetDevice(&dev);
        (void)hipDeviceGetAttribute(&coop_attr, hipDeviceAttributeCooperativeLaunch, dev);
        (void)hipDeviceGetAttribute(&ncu, hipDeviceAttributeMultiprocessorCount, dev);
        hipError_t e = hipOccupancyMaxActiveBlocksPerMultiprocessor(&occ, k_halfstep, 256, 0);
        coop_mode = (coop_attr && e == hipSuccess && (long)occ * ncu >= NBLK) ? 1 : 0;
    }

    float* ws = (float*)d_ws;
    // BIG aliased region: Apad (buildA..invert) vs tpart (iteration phases).
    // Apad = KCH*4096*144 = 9,437,184 f; tpart = 64*4096*16 = 4,194,304 f.
    float* big    = ws;
    float* Apad   = big;
    float* tpart  = big;
    float* endbig = big + (size_t)KCH * DIM * NPKP;
    float* Ainv   = endbig;                       // 4096*256
    float* snum   = Ainv + (size_t)DIM * 256;     // 2*4096 (ping-pong psi2 sums)
    float* cntc   = snum + 2 * DIM;               // 4096
    float* cntr   = cntc + DIM;                   // 4096
    float* Uc     = cntr + DIM;                   // 4096*16
    float* Vtb    = Uc + (size_t)DIM * RDIM;      // 4096*16
    unsigned short* Pt = (unsigned short*)(Vtb + (size_t)DIM * RDIM); // 144*4096 u16
    float* Xt     = out;  // reuse d_out as transpose scratch until k_out

    // zero the atomic count targets (cntc, cntr — contiguous)
    hipMemsetAsync(cntc, 0, (size_t)2 * DIM * sizeof(float), stream);

    k_transpose<<<dim3(64, 64), 256, 0, stream>>>(X, Xt, cntc, cntr);
    k_init_uc<<<64, 256, 0, stream>>>(U, Uc);
    k_init_vt<<<16, 256, 0, stream>>>(V, Vtb);
    // only Pt build not fused into a half-step: layer-0 V step from initial Uc
    k_prep<<<dim3(16, NPKP), 256, 0, stream>>>(Uc, Pt);

    for (int layer = 0; layer < 3; ++layer) {
        int last = (layer == 2);
        // ---- V step: design Uc, beta Vtb; mask rows from Xt, iter rows from X
        HSArgs hv;
        hv.XpT = Xt;  hv.Xp = X;   hv.PtIn = Pt; hv.PtOut = Pt;
        hv.Apad = Apad; hv.Ainv = Ainv; hv.tpart = tpart; hv.snum = snum;
        hv.sigma = sigma; hv.cnt = cntc;
        hv.cvec = cvec; hv.lvec = lvec; hv.mvec = mvec;
        hv.D = Uc; hv.B = Vtb; hv.layer = layer; hv.do_pt = 1;
        run_halfstep(hv, stream, coop_mode);

        // ---- U step: design Vtb, beta Uc; mask rows from X, iter rows from Xt
        HSArgs hu;
        hu.XpT = X;   hu.Xp = Xt;  hu.PtIn = Pt; hu.PtOut = last ? nullptr : Pt;
        hu.Apad = Apad; hu.Ainv = Ainv; hu.tpart = tpart; hu.snum = snum;
        hu.sigma = sigma; hu.cnt = cntr;
        hu.cvec = cvec; hu.lvec = lvec; hu.mvec = mvec;
        hu.D = Vtb; hu.B = Uc; hu.layer = layer; hu.do_pt = last ? 0 : 1;
        run_halfstep(hu, stream, coop_mode);
    }
    k_out<<<dim3(16, 64), 256, 0, stream>>>(Uc, Vtb, out);
}